// Round 7
// baseline (383.795 us; speedup 1.0000x reference)
//
#include <hip/hip_runtime.h>
#include <stdint.h>

#define BB 8
#define NN 100000
#define CC 18
#define DD 128
#define NCROSS 1024
#define TOPK 256
#define NBINS 8192
#define CCAP 4096
#define SEG 3125          // NN / 32
#define NITER 391         // ceil(NN / 256)
#define K2BINS 2048       // key>>19 <= 2032 for s in (0,1]

// d_out float offsets (outputs concatenated flat in return order)
#define OFF_PTS 0
#define OFF_FEAT 6144
#define OFF_SI 268288
#define OFF_CROSS 270336

// sigmoid with correctly-rounded f32 exp (exp computed in double, rounded to
// f32, then f32 arithmetic) — bit-matched numpy f32 pipeline (r1-r3 absmax=0)
__device__ __forceinline__ float sigf(float x) {
  float e = (float)exp(-(double)x);
  return 1.0f / (1.0f + e);
}

__global__ void k_init(uint32_t* __restrict__ p, int n) {
  int i = blockIdx.x * 256 + threadIdx.x;
  if (i < n) p[i] = 0u;
}

// PROVEN GREEN (r2 bench, 158 us): 32 blocks/batch, u32 LDS hist, atomic flush.
__global__ void k_score(const float* __restrict__ cen, const float* __restrict__ cls,
                        uint32_t* __restrict__ keys, uint32_t* __restrict__ hist) {
  int b = blockIdx.y;
  int seg = blockIdx.x;
  __shared__ uint32_t h[NBINS];  // 32 KB
  for (int j = threadIdx.x; j < NBINS; j += 256) h[j] = 0u;
  __syncthreads();
  int base = b * NN + seg * SEG;
  for (int it = threadIdx.x; it < SEG; it += 256) {
    int i = base + it;
    const float2* p2 = (const float2*)(cls + (size_t)i * CC);
    float m = -INFINITY;
#pragma unroll
    for (int c = 0; c < CC / 2; ++c) {
      float2 v = p2[c];
      m = fmaxf(m, fmaxf(v.x, v.y));
    }
    float s = sigf(m) * sigf(cen[i]);
    uint32_t k = __float_as_uint(s);
    keys[i] = k;
    atomicAdd(&h[k >> 19], 1u);
  }
  __syncthreads();
  for (int j = threadIdx.x; j < NBINS; j += 256) {
    uint32_t v = h[j];
    if (v) atomicAdd(&hist[b * NBINS + j], v);
  }
}

// PROVEN GREEN verbatim.
__global__ void k_select(const uint32_t* __restrict__ hist, uint32_t* __restrict__ cutoff) {
  int b = blockIdx.x;
  int t = threadIdx.x;
  __shared__ uint32_t h[NBINS];     // 32 KB
  __shared__ uint32_t csum[256];
  for (int j = t; j < NBINS; j += 256) h[j] = hist[b * NBINS + j];
  __syncthreads();
  uint32_t s = 0;
  int base = t * 32;
#pragma unroll
  for (int j = 0; j < 32; ++j) s += h[base + ((j + t) & 31)];
  csum[t] = s;
  __syncthreads();
  for (int off = 1; off < 256; off <<= 1) {
    uint32_t v = csum[t];
    uint32_t a = (t + off < 256) ? csum[t + off] : 0u;
    __syncthreads();
    csum[t] = v + a;
    __syncthreads();
  }
  uint32_t St = csum[t];
  uint32_t St1 = (t < 255) ? csum[t + 1] : 0u;
  if (St >= NCROSS && St1 < NCROSS) {
    uint32_t acc = St1;
    int cb = base;
    for (int bin = base + 31; bin >= base; --bin) {
      acc += h[bin];
      if (acc >= NCROSS) { cb = bin; break; }
    }
    cutoff[b] = (uint32_t)cb;
  }
}

// PROVEN GREEN verbatim: wave-aggregated atomics.
__global__ void k_compact(const uint32_t* __restrict__ keys, const uint32_t* __restrict__ cutoff,
                          uint32_t* __restrict__ cand_cnt, uint32_t* __restrict__ cand_key,
                          uint32_t* __restrict__ cand_idx) {
  int b = blockIdx.y;
  int n = blockIdx.x * 256 + threadIdx.x;
  bool pass = false;
  uint32_t k = 0;
  if (n < NN) {
    k = keys[b * NN + n];
    pass = (k >> 19) >= cutoff[b];
  }
  int lane = threadIdx.x & 63;
  unsigned long long mask = __ballot(pass);
  if (mask) {
    int leader = __ffsll(mask) - 1;
    uint32_t wbase = 0;
    if (lane == leader) wbase = atomicAdd(&cand_cnt[b], (uint32_t)__popcll(mask));
    wbase = __shfl(wbase, leader);
    if (pass) {
      uint32_t pos = wbase + (uint32_t)__popcll(mask & ((1ull << lane) - 1ull));
      if (pos < CCAP) {
        cand_key[b * CCAP + pos] = k;
        cand_idx[b * CCAP + pos] = (uint32_t)n;
      }
    }
  }
}

// PROVEN GREEN verbatim.
__global__ void k_rank(const uint32_t* __restrict__ cand_cnt, const uint32_t* __restrict__ cand_key,
                       const uint32_t* __restrict__ cand_idx, uint32_t* __restrict__ ordered) {
  int b = blockIdx.y;
  int g = blockIdx.x;
  uint32_t cnt = cand_cnt[b];
  if (cnt > CCAP) cnt = CCAP;
  int base = g * 256;
  if (base >= (int)cnt) return;
  __shared__ uint64_t comp[CCAP];  // 32 KB
  for (int j = threadIdx.x; j < (int)cnt; j += 256) {
    comp[j] = ((uint64_t)cand_key[b * CCAP + j] << 32) | (uint32_t)(~cand_idx[b * CCAP + j]);
  }
  __syncthreads();
  int j0 = base + threadIdx.x;
  if (j0 < (int)cnt) {
    uint64_t mine = comp[j0];
    uint32_t r = 0;
    for (uint32_t j = 0; j < cnt; ++j) r += (comp[j] > mine) ? 1u : 0u;
    if (r < NCROSS) ordered[b * NCROSS + r] = ~(uint32_t)mine;
  }
}

// DEAD TEST (A/B): the suspect merged select+compact+rank kernel, self-
// contained (reads only `keys`), writing to a scratch region nobody consumes.
// If this kernel faults internally, the bench crashes -> indicted.
// If the bench passes, the kernel is exonerated as a fault source.
__global__ void k2b_dummy(const uint32_t* __restrict__ keys, uint32_t* __restrict__ dummy) {
  int b = blockIdx.y;
  int slice = blockIdx.x;
  int t = threadIdx.x;
  __shared__ uint32_t hist2[K2BINS];  // 8 KB
  __shared__ uint32_t csum[256];
  __shared__ uint64_t comp[CCAP];     // 32 KB
  __shared__ uint32_t lcnt;
  __shared__ uint32_t s_cut;
  if (t == 0) { lcnt = 0u; s_cut = 0u; }
  for (int j = t; j < K2BINS; j += 256) hist2[j] = 0u;
  __syncthreads();
  const uint32_t* kb = keys + (size_t)b * NN;
  for (int it = 0; it < NITER; ++it) {
    int n = it * 256 + t;
    if (n < NN) atomicAdd(&hist2[(kb[n] >> 19) & (K2BINS - 1)], 1u);
  }
  __syncthreads();
  uint32_t s8 = 0;
  int cbase = t * 8;
#pragma unroll
  for (int j = 0; j < 8; ++j) s8 += hist2[cbase + ((j + t) & 7)];
  csum[t] = s8;
  __syncthreads();
  for (int off = 1; off < 256; off <<= 1) {
    uint32_t v = csum[t];
    uint32_t a = (t + off < 256) ? csum[t + off] : 0u;
    __syncthreads();
    csum[t] = v + a;
    __syncthreads();
  }
  uint32_t St = csum[t];
  uint32_t St1 = (t < 255) ? csum[t + 1] : 0u;
  if (St >= NCROSS && St1 < NCROSS) {
    uint32_t acc = St1;
    int cb = cbase;
    for (int bin = cbase + 7; bin >= cbase; --bin) {
      acc += hist2[bin];
      if (acc >= NCROSS) { cb = bin; break; }
    }
    s_cut = (uint32_t)cb;
  }
  __syncthreads();
  uint32_t cut = s_cut;
  for (int it = 0; it < NITER; ++it) {
    int n = it * 256 + t;
    bool pass = false;
    uint32_t k = 0;
    if (n < NN) {
      k = kb[n];
      pass = (k >> 19) >= cut;
    }
    unsigned long long m = __ballot(pass);
    if (m) {
      int lane = t & 63;
      int leader = __ffsll(m) - 1;
      uint32_t wb = 0;
      if (lane == leader) wb = atomicAdd(&lcnt, (uint32_t)__popcll(m));
      wb = __shfl(wb, leader);
      if (pass) {
        uint32_t pos = wb + (uint32_t)__popcll(m & ((1ull << lane) - 1ull));
        if (pos < CCAP) comp[pos] = ((uint64_t)k << 32) | (uint32_t)(~n);
      }
    }
  }
  __syncthreads();
  uint32_t cnt = lcnt < CCAP ? lcnt : CCAP;
  uint32_t per = (cnt + 7) >> 3;
  uint32_t j0b = (uint32_t)slice * per;
  uint32_t j0e = j0b + per;
  if (j0e > cnt) j0e = cnt;
  for (uint32_t j0 = j0b + t; j0 < j0e; j0 += 256) {
    uint64_t mine = comp[j0];
    uint32_t r = 0;
    for (uint32_t j = 0; j < cnt; ++j) r += (comp[j] > mine) ? 1u : 0u;
    if (r < NCROSS) dummy[b * NCROSS + r] = ~(uint32_t)mine;
  }
}

// PROVEN GREEN verbatim.
__global__ void k_sort256(const uint32_t* __restrict__ ordered, uint32_t* __restrict__ sel,
                          float* __restrict__ out_si) {
  int b = blockIdx.x;
  int t = threadIdx.x;
  __shared__ uint32_t idxs[TOPK];
  uint32_t v = ordered[b * NCROSS + t];
  idxs[t] = v;
  __syncthreads();
  int r = 0;
  for (int j = 0; j < TOPK; ++j) r += (idxs[j] < v) ? 1 : 0;
  sel[b * TOPK + r] = v;
  out_si[b * TOPK + r] = (float)v;
}

// PROVEN GREEN verbatim.
__global__ void k_gather(const float* __restrict__ features, const float* __restrict__ points,
                         const uint32_t* __restrict__ ordered, const uint32_t* __restrict__ sel,
                         float* __restrict__ out) {
  int g = blockIdx.x;
  int t = threadIdx.x;
  if (g < 1024) {
    int flat = g * 256 + t;
    int row = flat >> 5;
    int c4 = flat & 31;
    int b = row >> 10, j = row & 1023;
    uint32_t idx = ordered[b * NCROSS + j];
    const float4* src = (const float4*)(features + ((size_t)b * NN + idx) * DD);
    ((float4*)(out + OFF_CROSS))[flat] = src[c4];
  } else if (g < 1280) {
    int flat = (g - 1024) * 256 + t;
    int row = flat >> 5;
    int c4 = flat & 31;
    int b = row >> 8, j = row & 255;
    uint32_t idx = sel[b * TOPK + j];
    const float4* src = (const float4*)(features + ((size_t)b * NN + idx) * DD);
    ((float4*)(out + OFF_FEAT))[flat] = src[c4];
  } else {
    int b = g - 1280;
    uint32_t idx = sel[b * TOPK + t];
    const float* src = points + ((size_t)b * NN + idx) * 3;
    float* dst = out + OFF_PTS + ((size_t)b * TOPK + t) * 3;
    dst[0] = src[0];
    dst[1] = src[1];
    dst[2] = src[2];
  }
}

extern "C" void kernel_launch(void* const* d_in, const int* in_sizes, int n_in,
                              void* d_out, int out_size, void* d_ws, size_t ws_size,
                              hipStream_t stream) {
  const float* cen  = (const float*)d_in[0];
  const float* cls  = (const float*)d_in[1];
  const float* pts  = (const float*)d_in[2];
  const float* feat = (const float*)d_in[3];
  float* out = (float*)d_out;

  uint32_t* ws = (uint32_t*)d_ws;
  uint32_t* hist     = ws;                      // BB*NBINS
  uint32_t* cand_cnt = hist + BB * NBINS;       // BB
  uint32_t* cutoff   = cand_cnt + BB;           // BB
  uint32_t* cand_key = cutoff + BB;             // BB*CCAP  (reused as k2b dummy sink)
  uint32_t* cand_idx = cand_key + BB * CCAP;    // BB*CCAP
  uint32_t* ordered  = cand_idx + BB * CCAP;    // BB*NCROSS
  uint32_t* sel      = ordered + BB * NCROSS;   // BB*TOPK
  uint32_t* keys     = sel + BB * TOPK;         // BB*NN   -> total 3.77 MB (proven)

  int nz = BB * NBINS + BB;  // hist + cand_cnt (adjacent)
  k_init<<<(nz + 255) / 256, 256, 0, stream>>>(hist, nz);
  k_score<<<dim3(32, BB), 256, 0, stream>>>(cen, cls, keys, hist);
  k_select<<<BB, 256, 0, stream>>>(hist, cutoff);
  k_compact<<<dim3((NN + 255) / 256, BB), 256, 0, stream>>>(keys, cutoff, cand_cnt, cand_key, cand_idx);
  k_rank<<<dim3(CCAP / 256, BB), 256, 0, stream>>>(cand_cnt, cand_key, cand_idx, ordered);
  // dead test: writes into cand_key region (unused after k_rank), output unconsumed
  k2b_dummy<<<dim3(8, BB), 256, 0, stream>>>(keys, cand_key);
  k_sort256<<<BB, 256, 0, stream>>>(ordered, sel, out + OFF_SI);
  k_gather<<<1288, 256, 0, stream>>>(feat, pts, ordered, sel, out);
}

// Round 8
// 182.346 us; speedup vs baseline: 2.1048x; 2.1048x over previous
//
#include <hip/hip_runtime.h>
#include <stdint.h>

#define BB 8
#define NN 100000
#define CC 18
#define DD 128
#define NCROSS 1024
#define TOPK 256
#define NBINS 8192
#define CCAP 4096
#define SEG 3125          // NN / 32

// d_out float offsets (outputs concatenated flat in return order)
#define OFF_PTS 0
#define OFF_FEAT 6144
#define OFF_SI 268288
#define OFF_CROSS 270336

// sigmoid with correctly-rounded f32 exp — bit-matched numpy f32 pipeline
__device__ __forceinline__ float sigf(float x) {
  float e = (float)exp(-(double)x);
  return 1.0f / (1.0f + e);
}

__global__ void k_init(uint32_t* __restrict__ p, int n) {
  int i = blockIdx.x * 256 + threadIdx.x;
  if (i < n) p[i] = 0u;
}

// PROVEN GREEN (r2 158us, r7): 32 blocks/batch, u32 LDS hist, atomic flush.
__global__ void k_score(const float* __restrict__ cen, const float* __restrict__ cls,
                        uint32_t* __restrict__ keys, uint32_t* __restrict__ hist) {
  int b = blockIdx.y;
  int seg = blockIdx.x;
  __shared__ uint32_t h[NBINS];  // 32 KB
  for (int j = threadIdx.x; j < NBINS; j += 256) h[j] = 0u;
  __syncthreads();
  int base = b * NN + seg * SEG;
  for (int it = threadIdx.x; it < SEG; it += 256) {
    int i = base + it;
    const float2* p2 = (const float2*)(cls + (size_t)i * CC);
    float m = -INFINITY;
#pragma unroll
    for (int c = 0; c < CC / 2; ++c) {
      float2 v = p2[c];
      m = fmaxf(m, fmaxf(v.x, v.y));
    }
    float s = sigf(m) * sigf(cen[i]);
    uint32_t k = __float_as_uint(s);
    keys[i] = k;
    atomicAdd(&h[k >> 19], 1u);
  }
  __syncthreads();
  for (int j = threadIdx.x; j < NBINS; j += 256) {
    uint32_t v = h[j];
    if (v) atomicAdd(&hist[b * NBINS + j], v);
  }
}

// PROVEN GREEN verbatim.
__global__ void k_select(const uint32_t* __restrict__ hist, uint32_t* __restrict__ cutoff) {
  int b = blockIdx.x;
  int t = threadIdx.x;
  __shared__ uint32_t h[NBINS];     // 32 KB
  __shared__ uint32_t csum[256];
  for (int j = t; j < NBINS; j += 256) h[j] = hist[b * NBINS + j];
  __syncthreads();
  uint32_t s = 0;
  int base = t * 32;
#pragma unroll
  for (int j = 0; j < 32; ++j) s += h[base + ((j + t) & 31)];
  csum[t] = s;
  __syncthreads();
  for (int off = 1; off < 256; off <<= 1) {
    uint32_t v = csum[t];
    uint32_t a = (t + off < 256) ? csum[t + off] : 0u;
    __syncthreads();
    csum[t] = v + a;
    __syncthreads();
  }
  uint32_t St = csum[t];
  uint32_t St1 = (t < 255) ? csum[t + 1] : 0u;
  if (St >= NCROSS && St1 < NCROSS) {
    uint32_t acc = St1;
    int cb = base;
    for (int bin = base + 31; bin >= base; --bin) {
      acc += h[bin];
      if (acc >= NCROSS) { cb = bin; break; }
    }
    cutoff[b] = (uint32_t)cb;
  }
}

// PROVEN GREEN verbatim: wave-aggregated atomics.
__global__ void k_compact(const uint32_t* __restrict__ keys, const uint32_t* __restrict__ cutoff,
                          uint32_t* __restrict__ cand_cnt, uint32_t* __restrict__ cand_key,
                          uint32_t* __restrict__ cand_idx) {
  int b = blockIdx.y;
  int n = blockIdx.x * 256 + threadIdx.x;
  bool pass = false;
  uint32_t k = 0;
  if (n < NN) {
    k = keys[b * NN + n];
    pass = (k >> 19) >= cutoff[b];
  }
  int lane = threadIdx.x & 63;
  unsigned long long mask = __ballot(pass);
  if (mask) {
    int leader = __ffsll(mask) - 1;
    uint32_t wbase = 0;
    if (lane == leader) wbase = atomicAdd(&cand_cnt[b], (uint32_t)__popcll(mask));
    wbase = __shfl(wbase, leader);
    if (pass) {
      uint32_t pos = wbase + (uint32_t)__popcll(mask & ((1ull << lane) - 1ull));
      if (pos < CCAP) {
        cand_key[b * CCAP + pos] = k;
        cand_idx[b * CCAP + pos] = (uint32_t)n;
      }
    }
  }
}

// PROVEN GREEN verbatim.
__global__ void k_rank(const uint32_t* __restrict__ cand_cnt, const uint32_t* __restrict__ cand_key,
                       const uint32_t* __restrict__ cand_idx, uint32_t* __restrict__ ordered) {
  int b = blockIdx.y;
  int g = blockIdx.x;
  uint32_t cnt = cand_cnt[b];
  if (cnt > CCAP) cnt = CCAP;
  int base = g * 256;
  if (base >= (int)cnt) return;
  __shared__ uint64_t comp[CCAP];  // 32 KB
  for (int j = threadIdx.x; j < (int)cnt; j += 256) {
    comp[j] = ((uint64_t)cand_key[b * CCAP + j] << 32) | (uint32_t)(~cand_idx[b * CCAP + j]);
  }
  __syncthreads();
  int j0 = base + threadIdx.x;
  if (j0 < (int)cnt) {
    uint64_t mine = comp[j0];
    uint32_t r = 0;
    for (uint32_t j = 0; j < cnt; ++j) r += (comp[j] > mine) ? 1u : 0u;
    if (r < NCROSS) ordered[b * NCROSS + r] = ~(uint32_t)mine;
  }
}

// PROVEN GREEN verbatim.
__global__ void k_sort256(const uint32_t* __restrict__ ordered, uint32_t* __restrict__ sel,
                          float* __restrict__ out_si) {
  int b = blockIdx.x;
  int t = threadIdx.x;
  __shared__ uint32_t idxs[TOPK];
  uint32_t v = ordered[b * NCROSS + t];
  idxs[t] = v;
  __syncthreads();
  int r = 0;
  for (int j = 0; j < TOPK; ++j) r += (idxs[j] < v) ? 1 : 0;
  sel[b * TOPK + r] = v;
  out_si[b * TOPK + r] = (float)v;
}

// PROVEN GREEN verbatim.
__global__ void k_gather(const float* __restrict__ features, const float* __restrict__ points,
                         const uint32_t* __restrict__ ordered, const uint32_t* __restrict__ sel,
                         float* __restrict__ out) {
  int g = blockIdx.x;
  int t = threadIdx.x;
  if (g < 1024) {
    int flat = g * 256 + t;
    int row = flat >> 5;
    int c4 = flat & 31;
    int b = row >> 10, j = row & 1023;
    uint32_t idx = ordered[b * NCROSS + j];
    const float4* src = (const float4*)(features + ((size_t)b * NN + idx) * DD);
    ((float4*)(out + OFF_CROSS))[flat] = src[c4];
  } else if (g < 1280) {
    int flat = (g - 1024) * 256 + t;
    int row = flat >> 5;
    int c4 = flat & 31;
    int b = row >> 8, j = row & 255;
    uint32_t idx = sel[b * TOPK + j];
    const float4* src = (const float4*)(features + ((size_t)b * NN + idx) * DD);
    ((float4*)(out + OFF_FEAT))[flat] = src[c4];
  } else {
    int b = g - 1280;
    uint32_t idx = sel[b * TOPK + t];
    const float* src = points + ((size_t)b * NN + idx) * 3;
    float* dst = out + OFF_PTS + ((size_t)b * TOPK + t) * 3;
    dst[0] = src[0];
    dst[1] = src[1];
    dst[2] = src[2];
  }
}

// GAP PROBE: zero-work dispatch (guard is never true; no memory traffic).
// 16 of these measure pure per-dispatch overhead in the captured graph.
__global__ void k_nop(uint32_t* p) {
  if (blockIdx.x == 0xFFFFFFFFu) p[0] = 0u;
}

extern "C" void kernel_launch(void* const* d_in, const int* in_sizes, int n_in,
                              void* d_out, int out_size, void* d_ws, size_t ws_size,
                              hipStream_t stream) {
  const float* cen  = (const float*)d_in[0];
  const float* cls  = (const float*)d_in[1];
  const float* pts  = (const float*)d_in[2];
  const float* feat = (const float*)d_in[3];
  float* out = (float*)d_out;

  uint32_t* ws = (uint32_t*)d_ws;
  uint32_t* hist     = ws;                      // BB*NBINS
  uint32_t* cand_cnt = hist + BB * NBINS;       // BB
  uint32_t* cutoff   = cand_cnt + BB;           // BB
  uint32_t* cand_key = cutoff + BB;             // BB*CCAP
  uint32_t* cand_idx = cand_key + BB * CCAP;    // BB*CCAP
  uint32_t* ordered  = cand_idx + BB * CCAP;    // BB*NCROSS
  uint32_t* sel      = ordered + BB * NCROSS;   // BB*TOPK
  uint32_t* keys     = sel + BB * TOPK;         // BB*NN   -> total 3.77 MB (proven)

  int nz = BB * NBINS + BB;  // hist + cand_cnt (adjacent)
  k_init<<<(nz + 255) / 256, 256, 0, stream>>>(hist, nz);
  k_score<<<dim3(32, BB), 256, 0, stream>>>(cen, cls, keys, hist);
  k_select<<<BB, 256, 0, stream>>>(hist, cutoff);
  k_compact<<<dim3((NN + 255) / 256, BB), 256, 0, stream>>>(keys, cutoff, cand_cnt, cand_key, cand_idx);
  k_rank<<<dim3(CCAP / 256, BB), 256, 0, stream>>>(cand_cnt, cand_key, cand_idx, ordered);
  k_sort256<<<BB, 256, 0, stream>>>(ordered, sel, out + OFF_SI);
  k_gather<<<1288, 256, 0, stream>>>(feat, pts, ordered, sel, out);
  // ---- gap probe: 16 zero-work dispatches ----
  for (int i = 0; i < 16; ++i) {
    k_nop<<<2048, 256, 0, stream>>>(hist);
  }
}

// Round 9
// 142.384 us; speedup vs baseline: 2.6955x; 1.2807x over previous
//
#include <hip/hip_runtime.h>
#include <stdint.h>

#define BB 8
#define NN 100000
#define CC 18
#define DD 128
#define NCROSS 1024
#define TOPK 256
#define NBINS 8192
#define CCAP 4096
#define SEG 3125          // NN / 32
#define RBLK 64           // positions per k_rank2 block

// d_out float offsets (outputs concatenated flat in return order)
#define OFF_PTS 0
#define OFF_FEAT 6144
#define OFF_SI 268288
#define OFF_CROSS 270336

// sigmoid with correctly-rounded f32 exp — bit-matched numpy f32 pipeline
__device__ __forceinline__ float sigf(float x) {
  float e = (float)exp(-(double)x);
  return 1.0f / (1.0f + e);
}

__global__ void k_init(uint32_t* __restrict__ p, int n) {
  int i = blockIdx.x * 256 + threadIdx.x;
  if (i < n) p[i] = 0u;
}

// PROVEN GREEN (r2 158us, r7, r8): 32 blocks/batch, u32 LDS hist, atomic flush.
__global__ void k_score(const float* __restrict__ cen, const float* __restrict__ cls,
                        uint32_t* __restrict__ keys, uint32_t* __restrict__ hist) {
  int b = blockIdx.y;
  int seg = blockIdx.x;
  __shared__ uint32_t h[NBINS];  // 32 KB
  for (int j = threadIdx.x; j < NBINS; j += 256) h[j] = 0u;
  __syncthreads();
  int base = b * NN + seg * SEG;
  for (int it = threadIdx.x; it < SEG; it += 256) {
    int i = base + it;
    const float2* p2 = (const float2*)(cls + (size_t)i * CC);
    float m = -INFINITY;
#pragma unroll
    for (int c = 0; c < CC / 2; ++c) {
      float2 v = p2[c];
      m = fmaxf(m, fmaxf(v.x, v.y));
    }
    float s = sigf(m) * sigf(cen[i]);
    uint32_t k = __float_as_uint(s);
    keys[i] = k;
    atomicAdd(&h[k >> 19], 1u);
  }
  __syncthreads();
  for (int j = threadIdx.x; j < NBINS; j += 256) {
    uint32_t v = h[j];
    if (v) atomicAdd(&hist[b * NBINS + j], v);
  }
}

// PROVEN GREEN verbatim.
__global__ void k_select(const uint32_t* __restrict__ hist, uint32_t* __restrict__ cutoff) {
  int b = blockIdx.x;
  int t = threadIdx.x;
  __shared__ uint32_t h[NBINS];     // 32 KB
  __shared__ uint32_t csum[256];
  for (int j = t; j < NBINS; j += 256) h[j] = hist[b * NBINS + j];
  __syncthreads();
  uint32_t s = 0;
  int base = t * 32;
#pragma unroll
  for (int j = 0; j < 32; ++j) s += h[base + ((j + t) & 31)];
  csum[t] = s;
  __syncthreads();
  for (int off = 1; off < 256; off <<= 1) {
    uint32_t v = csum[t];
    uint32_t a = (t + off < 256) ? csum[t + off] : 0u;
    __syncthreads();
    csum[t] = v + a;
    __syncthreads();
  }
  uint32_t St = csum[t];
  uint32_t St1 = (t < 255) ? csum[t + 1] : 0u;
  if (St >= NCROSS && St1 < NCROSS) {
    uint32_t acc = St1;
    int cb = base;
    for (int bin = base + 31; bin >= base; --bin) {
      acc += h[bin];
      if (acc >= NCROSS) { cb = bin; break; }
    }
    cutoff[b] = (uint32_t)cb;
  }
}

// PROVEN GREEN verbatim: wave-aggregated atomics.
__global__ void k_compact(const uint32_t* __restrict__ keys, const uint32_t* __restrict__ cutoff,
                          uint32_t* __restrict__ cand_cnt, uint32_t* __restrict__ cand_key,
                          uint32_t* __restrict__ cand_idx) {
  int b = blockIdx.y;
  int n = blockIdx.x * 256 + threadIdx.x;
  bool pass = false;
  uint32_t k = 0;
  if (n < NN) {
    k = keys[b * NN + n];
    pass = (k >> 19) >= cutoff[b];
  }
  int lane = threadIdx.x & 63;
  unsigned long long mask = __ballot(pass);
  if (mask) {
    int leader = __ffsll(mask) - 1;
    uint32_t wbase = 0;
    if (lane == leader) wbase = atomicAdd(&cand_cnt[b], (uint32_t)__popcll(mask));
    wbase = __shfl(wbase, leader);
    if (pass) {
      uint32_t pos = wbase + (uint32_t)__popcll(mask & ((1ull << lane) - 1ull));
      if (pos < CCAP) {
        cand_key[b * CCAP + pos] = k;
        cand_idx[b * CCAP + pos] = (uint32_t)n;
      }
    }
  }
}

// NEW: latency-fixed ranking. 512 blocks (64 positions each, 2 blocks/CU).
// Each position is ranked by 4 waves scanning disjoint quarters of comp[];
// within a wave all 64 lanes read the SAME comp[j] (LDS broadcast, zero
// conflicts). Partial counts combine via LDS atomicAdd (order-independent).
__global__ void k_rank2(const uint32_t* __restrict__ cand_cnt, const uint32_t* __restrict__ cand_key,
                        const uint32_t* __restrict__ cand_idx, uint32_t* __restrict__ ordered) {
  int b = blockIdx.y;
  uint32_t cnt = cand_cnt[b];
  if (cnt > CCAP) cnt = CCAP;
  uint32_t base = blockIdx.x * RBLK;
  if (base >= cnt) return;  // uniform per block
  __shared__ uint64_t comp[CCAP];   // 32 KB
  __shared__ uint32_t rsum[RBLK];
  int t = threadIdx.x;
  for (uint32_t j = t; j < cnt; j += 256) {
    comp[j] = ((uint64_t)cand_key[b * CCAP + j] << 32) | (uint32_t)(~cand_idx[b * CCAP + j]);
  }
  if (t < RBLK) rsum[t] = 0u;
  __syncthreads();
  uint32_t p = base + (t & 63);     // position: one per lane
  int part = t >> 6;                // wave id = quarter of the scan range
  if (p < cnt) {
    uint64_t mine = comp[p];
    uint32_t lo = (cnt * (uint32_t)part) >> 2;
    uint32_t hi = (cnt * (uint32_t)(part + 1)) >> 2;
    uint32_t r = 0;
    uint32_t j = lo;
    for (; j + 8 <= hi; j += 8) {   // broadcast reads, 8x unrolled
      uint64_t c0 = comp[j], c1 = comp[j + 1], c2 = comp[j + 2], c3 = comp[j + 3];
      uint64_t c4 = comp[j + 4], c5 = comp[j + 5], c6 = comp[j + 6], c7 = comp[j + 7];
      r += (c0 > mine) + (c1 > mine) + (c2 > mine) + (c3 > mine);
      r += (c4 > mine) + (c5 > mine) + (c6 > mine) + (c7 > mine);
    }
    for (; j < hi; ++j) r += (comp[j] > mine) ? 1u : 0u;
    atomicAdd(&rsum[t & 63], r);
  }
  __syncthreads();
  if (part == 0 && p < cnt) {
    uint32_t r = rsum[t & 63];
    if (r < NCROSS) ordered[b * NCROSS + r] = ~(uint32_t)comp[p];
  }
}

// PROVEN GREEN verbatim.
__global__ void k_sort256(const uint32_t* __restrict__ ordered, uint32_t* __restrict__ sel,
                          float* __restrict__ out_si) {
  int b = blockIdx.x;
  int t = threadIdx.x;
  __shared__ uint32_t idxs[TOPK];
  uint32_t v = ordered[b * NCROSS + t];
  idxs[t] = v;
  __syncthreads();
  int r = 0;
  for (int j = 0; j < TOPK; ++j) r += (idxs[j] < v) ? 1 : 0;
  sel[b * TOPK + r] = v;
  out_si[b * TOPK + r] = (float)v;
}

// PROVEN GREEN verbatim.
__global__ void k_gather(const float* __restrict__ features, const float* __restrict__ points,
                         const uint32_t* __restrict__ ordered, const uint32_t* __restrict__ sel,
                         float* __restrict__ out) {
  int g = blockIdx.x;
  int t = threadIdx.x;
  if (g < 1024) {
    int flat = g * 256 + t;
    int row = flat >> 5;
    int c4 = flat & 31;
    int b = row >> 10, j = row & 1023;
    uint32_t idx = ordered[b * NCROSS + j];
    const float4* src = (const float4*)(features + ((size_t)b * NN + idx) * DD);
    ((float4*)(out + OFF_CROSS))[flat] = src[c4];
  } else if (g < 1280) {
    int flat = (g - 1024) * 256 + t;
    int row = flat >> 5;
    int c4 = flat & 31;
    int b = row >> 8, j = row & 255;
    uint32_t idx = sel[b * TOPK + j];
    const float4* src = (const float4*)(features + ((size_t)b * NN + idx) * DD);
    ((float4*)(out + OFF_FEAT))[flat] = src[c4];
  } else {
    int b = g - 1280;
    uint32_t idx = sel[b * TOPK + t];
    const float* src = points + ((size_t)b * NN + idx) * 3;
    float* dst = out + OFF_PTS + ((size_t)b * TOPK + t) * 3;
    dst[0] = src[0];
    dst[1] = src[1];
    dst[2] = src[2];
  }
}

extern "C" void kernel_launch(void* const* d_in, const int* in_sizes, int n_in,
                              void* d_out, int out_size, void* d_ws, size_t ws_size,
                              hipStream_t stream) {
  const float* cen  = (const float*)d_in[0];
  const float* cls  = (const float*)d_in[1];
  const float* pts  = (const float*)d_in[2];
  const float* feat = (const float*)d_in[3];
  float* out = (float*)d_out;

  uint32_t* ws = (uint32_t*)d_ws;
  uint32_t* hist     = ws;                      // BB*NBINS
  uint32_t* cand_cnt = hist + BB * NBINS;       // BB
  uint32_t* cutoff   = cand_cnt + BB;           // BB
  uint32_t* cand_key = cutoff + BB;             // BB*CCAP
  uint32_t* cand_idx = cand_key + BB * CCAP;    // BB*CCAP
  uint32_t* ordered  = cand_idx + BB * CCAP;    // BB*NCROSS
  uint32_t* sel      = ordered + BB * NCROSS;   // BB*TOPK
  uint32_t* keys     = sel + BB * TOPK;         // BB*NN   -> total 3.77 MB (proven)

  int nz = BB * NBINS + BB;  // hist + cand_cnt (adjacent)
  k_init<<<(nz + 255) / 256, 256, 0, stream>>>(hist, nz);
  k_score<<<dim3(32, BB), 256, 0, stream>>>(cen, cls, keys, hist);
  k_select<<<BB, 256, 0, stream>>>(hist, cutoff);
  k_compact<<<dim3((NN + 255) / 256, BB), 256, 0, stream>>>(keys, cutoff, cand_cnt, cand_key, cand_idx);
  k_rank2<<<dim3(CCAP / RBLK, BB), 256, 0, stream>>>(cand_cnt, cand_key, cand_idx, ordered);
  k_sort256<<<BB, 256, 0, stream>>>(ordered, sel, out + OFF_SI);
  k_gather<<<1288, 256, 0, stream>>>(feat, pts, ordered, sel, out);
}